// Round 5
// baseline (246.857 us; speedup 1.0000x reference)
//
#include <hip/hip_runtime.h>

// SimpleGraphSAGE: out = mean_agg(x[src]->dst) @ W_l + b_l + x @ W_r
// N=50000, E=640000, IN=128, HID=256.
// R5: fuse aggregation into the GEMM. Block owns 64 rows:
//   phase 0: stage bf16(x) half of A-tile global->LDS (rows' cols 128..255)
//   phase 1: gather-reduce neighbor means DIRECTLY into LDS A-tile cols 0..127
//   (one barrier)
//   phase 2: barrier-free MFMA K-loop; B-fragments loaded straight from
//   global Wimg (pre-tiled so the load is a coalesced 16B/lane b128).
// Mean matrix never touches global memory (saves 25.6 MB round-trip + 1 launch).

constexpr int N_NODES = 50000;
constexpr int N_EDGES = 640000;
constexpr int SCAN_BLOCKS = (N_NODES + 256) / 256;  // 196, covers i==N_NODES

constexpr int HIST_BLOCKS  = N_EDGES / 1024;        // 625, thread handles 4 edges
constexpr int PREPX_BLOCKS = N_NODES * 32 / 256;    // 6250, thread = 4 channels
constexpr int WPREP_BLOCKS = 256;                   // 65536 weight elems

typedef __attribute__((ext_vector_type(8))) short short8;
typedef __attribute__((ext_vector_type(4))) float f32x4;

__device__ inline unsigned short f2bf(float f) {
    unsigned int u = __float_as_uint(f);
    u += 0x7fff + ((u >> 16) & 1);  // RNE
    return (unsigned short)(u >> 16);
}
__device__ inline float bf2f(unsigned int s) {
    return __uint_as_float(s << 16);
}

// ---------------------------------------------------------------------------
// prep_k: block-range fused  [hist | x->bf16 | W->bf16 tiled]
// Abf row layout: [0..127]=unused, [128..255]=bf16(x row)  (kept from R4)
// ---------------------------------------------------------------------------
__global__ __launch_bounds__(256) void prep_k(const float* __restrict__ x,
                                              const int* __restrict__ ei,
                                              const float* __restrict__ Wl,
                                              const float* __restrict__ Wr,
                                              unsigned int* __restrict__ Abf_u,
                                              unsigned short* __restrict__ Wimg,
                                              int* __restrict__ cnt) {
    int bid = blockIdx.x, tid = threadIdx.x;
    if (bid < HIST_BLOCKS) {
        int base = bid * 1024 + tid;
#pragma unroll
        for (int k = 0; k < 4; k++)
            atomicAdd(&cnt[ei[N_EDGES + base + k * 256]], 1);
    } else if (bid < HIST_BLOCKS + PREPX_BLOCKS) {
        int t = (bid - HIST_BLOCKS) * 256 + tid;          // < N*32
        float4 v = reinterpret_cast<const float4*>(x)[t];
        unsigned int p0 = (unsigned int)f2bf(v.x) | ((unsigned int)f2bf(v.y) << 16);
        unsigned int p1 = (unsigned int)f2bf(v.z) | ((unsigned int)f2bf(v.w) << 16);
        int row = t >> 5, c = t & 31;
        reinterpret_cast<uint2*>(Abf_u)[(size_t)row * 64 + 32 + c] =
            make_uint2(p0, p1);
    } else {
        int t = (bid - HIST_BLOCKS - PREPX_BLOCKS) * 256 + tid;  // < 65536
        int k = t >> 8, n = t & 255;
        float v = (k < 128) ? Wl[k * 256 + n] : Wr[(k - 128) * 256 + n];
        Wimg[(size_t)(k >> 5) * 8192 + n * 32 + (k & 31)] = f2bf(v);
    }
}

// ---------------------------------------------------------------------------
// CSR build: scan + permute
// ---------------------------------------------------------------------------
__device__ inline int block_scan_excl(int v, int tid, int* tmp) {
    tmp[tid] = v;
    __syncthreads();
#pragma unroll
    for (int off = 1; off < 256; off <<= 1) {
        int t = (tid >= off) ? tmp[tid - off] : 0;
        __syncthreads();
        tmp[tid] += t;
        __syncthreads();
    }
    return tmp[tid] - v;
}

__global__ __launch_bounds__(256) void scan1_k(const int* __restrict__ cnt,
                                               int* __restrict__ blockSums) {
    __shared__ int tmp[256];
    int i = blockIdx.x * 256 + threadIdx.x;
    int v = (i < N_NODES) ? cnt[i] : 0;
    block_scan_excl(v, threadIdx.x, tmp);
    if (threadIdx.x == 255) blockSums[blockIdx.x] = tmp[255];
}

__global__ __launch_bounds__(256) void scan23_k(const int* __restrict__ cnt,
                                                const int* __restrict__ blockSums,
                                                int* __restrict__ row_start,
                                                int* __restrict__ cursor) {
    __shared__ int red[256];
    __shared__ int tmp[256];
    int tid = threadIdx.x;
    int bv = (tid < (int)blockIdx.x) ? blockSums[tid] : 0;
    red[tid] = bv;
    __syncthreads();
#pragma unroll
    for (int off = 128; off > 0; off >>= 1) {
        if (tid < off) red[tid] += red[tid + off];
        __syncthreads();
    }
    int boff = red[0];
    int i = blockIdx.x * 256 + tid;
    int v = (i < N_NODES) ? cnt[i] : 0;
    int ex = block_scan_excl(v, tid, tmp);
    int rs = boff + ex;
    if (i < N_NODES) {
        row_start[i] = rs;
        cursor[i]    = rs;
    }
    if (i == N_NODES) row_start[N_NODES] = rs;
}

__global__ __launch_bounds__(256) void permute_k(const int* __restrict__ ei,
                                                 int* __restrict__ cursor,
                                                 int* __restrict__ sorted_src) {
    int e = blockIdx.x * 256 + threadIdx.x;
    if (e >= N_EDGES) return;
    int dst = ei[N_EDGES + e];
    int pos = atomicAdd(&cursor[dst], 1);
    sorted_src[pos] = ei[e];
}

// ---------------------------------------------------------------------------
// fused_k: 64 rows x 256 cols per block (4 waves).
// LDS: Ms[64][264] bf16 = full A-tile [mean | x], stride 264 (528B, 16B-mult).
// Phase 0: stage x-half (cols 128..255).
// Phase 1: wave w computes means for its 16 rows: lane=(g=lane>>4, sub=lane&15),
//   one b128 load covers 4 edges, unroll x2 = 8 edges in flight; shfl_xor(16,32)
//   folds edge groups; g==0 lanes write 16B each into Ms cols 0..127.
// Phase 2 (one barrier before): 8 K-steps, A-frags from LDS, B-frags straight
//   from global Wimg (coalesced b128), 16 MFMA per step, NO further barriers.
// ---------------------------------------------------------------------------
__global__ __launch_bounds__(256) void fused_k(const int* __restrict__ row_start,
                                               const int* __restrict__ sorted_src,
                                               const unsigned int* __restrict__ Abf_u,
                                               const unsigned short* __restrict__ Wimg,
                                               const float* __restrict__ bl,
                                               float* __restrict__ out) {
    __shared__ unsigned short Ms[64 * 264];

    int tid  = threadIdx.x;
    int w    = tid >> 6;
    int lane = tid & 63;
    int g    = lane >> 4;     // also 'quad' in MFMA terms
    int sub  = lane & 15;     // also 'm15'
    int bm   = blockIdx.x * 64;

    const unsigned short* Abf = reinterpret_cast<const unsigned short*>(Abf_u);
    const uint4* X = reinterpret_cast<const uint4*>(Abf_u);  // row = 32 uint4

    // ---- phase 0: stage x-half: 64 rows x 16 chunks of 8 bf16 ----
#pragma unroll
    for (int s = 0; s < 4; s++) {
        int idx = s * 256 + tid;
        int r = idx >> 4, c = idx & 15;
        int grow = bm + r;
        short8 v = {0, 0, 0, 0, 0, 0, 0, 0};
        if (grow < N_NODES)
            v = *reinterpret_cast<const short8*>(Abf + (size_t)grow * 256 + 128 + c * 8);
        *reinterpret_cast<short8*>(Ms + r * 264 + 128 + c * 8) = v;
    }

    // ---- phase 1: means for rows [bm + w*16, bm + w*16 + 16) ----
    for (int n = 0; n < 16; n++) {
        int node = bm + w * 16 + n;
        int beg = 0, end = 0;
        if (node < N_NODES) {
            beg = row_start[node];
            end = row_start[node + 1];
        }
        float s[8];
#pragma unroll
        for (int j = 0; j < 8; j++) s[j] = 0.f;

        for (int i = beg; i < end; i += 8) {
            int e0 = i + g;
            int e1 = i + 4 + g;
            uint4 v0 = make_uint4(0, 0, 0, 0), v1 = make_uint4(0, 0, 0, 0);
            if (e0 < end) v0 = X[(size_t)sorted_src[e0] * 32 + 16 + sub];
            if (e1 < end) v1 = X[(size_t)sorted_src[e1] * 32 + 16 + sub];
            s[0] += bf2f(v0.x & 0xffffu) + bf2f(v1.x & 0xffffu);
            s[1] += bf2f(v0.x >> 16)     + bf2f(v1.x >> 16);
            s[2] += bf2f(v0.y & 0xffffu) + bf2f(v1.y & 0xffffu);
            s[3] += bf2f(v0.y >> 16)     + bf2f(v1.y >> 16);
            s[4] += bf2f(v0.z & 0xffffu) + bf2f(v1.z & 0xffffu);
            s[5] += bf2f(v0.z >> 16)     + bf2f(v1.z >> 16);
            s[6] += bf2f(v0.w & 0xffffu) + bf2f(v1.w & 0xffffu);
            s[7] += bf2f(v0.w >> 16)     + bf2f(v1.w >> 16);
        }

#pragma unroll
        for (int m = 16; m <= 32; m <<= 1)
#pragma unroll
            for (int j = 0; j < 8; j++) s[j] += __shfl_xor(s[j], m, 64);

        if (g == 0) {
            float inv = (end > beg) ? 1.0f / (float)(end - beg) : 0.0f;
            uint4 o;
            o.x = (unsigned int)f2bf(s[0] * inv) | ((unsigned int)f2bf(s[1] * inv) << 16);
            o.y = (unsigned int)f2bf(s[2] * inv) | ((unsigned int)f2bf(s[3] * inv) << 16);
            o.z = (unsigned int)f2bf(s[4] * inv) | ((unsigned int)f2bf(s[5] * inv) << 16);
            o.w = (unsigned int)f2bf(s[6] * inv) | ((unsigned int)f2bf(s[7] * inv) << 16);
            *reinterpret_cast<uint4*>(Ms + (w * 16 + n) * 264 + sub * 8) = o;
        }
    }

    __syncthreads();  // the only barrier

    // ---- phase 2: MFMA K-loop, barrier-free ----
    int m15 = sub, quad = g;
    f32x4 zero4 = {0.f, 0.f, 0.f, 0.f};
    f32x4 acc[4][4];
#pragma unroll
    for (int rt = 0; rt < 4; rt++)
#pragma unroll
        for (int ct = 0; ct < 4; ct++) acc[rt][ct] = zero4;

#pragma unroll
    for (int kc = 0; kc < 8; kc++) {
        short8 Af[4], Bf[4];
#pragma unroll
        for (int rt = 0; rt < 4; rt++)
            Af[rt] = *reinterpret_cast<const short8*>(
                         Ms + (rt * 16 + m15) * 264 + kc * 32 + quad * 8);
#pragma unroll
        for (int ct = 0; ct < 4; ct++)
            Bf[ct] = *reinterpret_cast<const short8*>(
                         Wimg + (size_t)kc * 8192 +
                         (w * 64 + ct * 16 + m15) * 32 + quad * 8);
#pragma unroll
        for (int rt = 0; rt < 4; rt++)
#pragma unroll
            for (int ct = 0; ct < 4; ct++)
                acc[rt][ct] = __builtin_amdgcn_mfma_f32_16x16x32_bf16(
                    Af[rt], Bf[ct], acc[rt][ct], 0, 0, 0);
    }

    // ---- epilogue: C/D layout col=lane&15, row=quad*4+reg ----
    float bias[4];
#pragma unroll
    for (int ct = 0; ct < 4; ct++) bias[ct] = bl[w * 64 + ct * 16 + m15];
#pragma unroll
    for (int rt = 0; rt < 4; rt++) {
        int rb = bm + rt * 16 + quad * 4;
#pragma unroll
        for (int r = 0; r < 4; r++) {
            int row = rb + r;
            if (row < N_NODES) {
#pragma unroll
                for (int ct = 0; ct < 4; ct++)
                    out[(size_t)row * 256 + w * 64 + ct * 16 + m15] =
                        acc[rt][ct][r] + bias[ct];
            }
        }
    }
}

extern "C" void kernel_launch(void* const* d_in, const int* in_sizes, int n_in,
                              void* d_out, int out_size, void* d_ws, size_t ws_size,
                              hipStream_t stream) {
    const float* x  = (const float*)d_in[0];
    const int*   ei = (const int*)d_in[1];   // [2, E] int32
    const float* Wl = (const float*)d_in[2];
    const float* bl = (const float*)d_in[3];
    const float* Wr = (const float*)d_in[4];
    float* out = (float*)d_out;

    // ws layout
    unsigned short* Abf  = (unsigned short*)d_ws;              // N*256 bf16
    unsigned short* Wimg = Abf + (size_t)N_NODES * 256;        // 65536 bf16
    int* cnt        = (int*)(Wimg + 65536);                    // N
    int* row_start  = cnt + N_NODES;                           // N+1
    int* cursor     = row_start + N_NODES + 1;                 // N
    int* blockSums  = cursor + N_NODES;                        // 256
    int* sorted_src = blockSums + 256;                         // E

    hipMemsetAsync(cnt, 0, N_NODES * sizeof(int), stream);

    prep_k<<<HIST_BLOCKS + PREPX_BLOCKS + WPREP_BLOCKS, 256, 0, stream>>>(
        x, ei, Wl, Wr, (unsigned int*)Abf, Wimg, cnt);
    scan1_k<<<SCAN_BLOCKS, 256, 0, stream>>>(cnt, blockSums);
    scan23_k<<<SCAN_BLOCKS, 256, 0, stream>>>(cnt, blockSums, row_start, cursor);
    permute_k<<<(N_EDGES + 255) / 256, 256, 0, stream>>>(ei, cursor, sorted_src);
    fused_k<<<(N_NODES + 63) / 64, 256, 0, stream>>>(row_start, sorted_src,
                                                     (unsigned int*)Abf, Wimg,
                                                     bl, out);
}

// Round 6
// 205.008 us; speedup vs baseline: 1.2041x; 1.2041x over previous
//
#include <hip/hip_runtime.h>

// SimpleGraphSAGE: out = mean_agg(x[src]->dst) @ W_l + b_l + x @ W_r
// N=50000, E=640000, IN=128, HID=256.
// R6: revert R5's fusion (TLP collapse: 3128 waves vs 50000 for the
// latency-bound gather). Keep R4's separate agg_k (1 wave/node).
// gemm_k upgraded with R5's sound part: stage full 64x256 A-tile once,
// ONE barrier, barrier-free unrolled K-loop, B-frags direct from global
// Wimg (L2-resident, coalesced 1KB/wave). Scans use wave-shfl (1 barrier).

constexpr int N_NODES = 50000;
constexpr int N_EDGES = 640000;
constexpr int SCAN_BLOCKS = (N_NODES + 256) / 256;  // 196, covers i==N_NODES

constexpr int HIST_BLOCKS  = N_EDGES / 1024;        // 625, thread handles 4 edges
constexpr int PREPX_BLOCKS = N_NODES * 32 / 256;    // 6250, thread = 4 channels
constexpr int WPREP_BLOCKS = 256;                   // 65536 weight elems

typedef __attribute__((ext_vector_type(8))) short short8;
typedef __attribute__((ext_vector_type(4))) float f32x4;

__device__ inline unsigned short f2bf(float f) {
    unsigned int u = __float_as_uint(f);
    u += 0x7fff + ((u >> 16) & 1);  // RNE
    return (unsigned short)(u >> 16);
}
__device__ inline float bf2f(unsigned int s) {
    return __uint_as_float(s << 16);
}

// ---------------------------------------------------------------------------
// prep_k: block-range fused  [hist | x->bf16 | W->bf16 tiled]
// Abf row layout: [0..127]=mean (agg_k), [128..255]=bf16(x row)
// ---------------------------------------------------------------------------
__global__ __launch_bounds__(256) void prep_k(const float* __restrict__ x,
                                              const int* __restrict__ ei,
                                              const float* __restrict__ Wl,
                                              const float* __restrict__ Wr,
                                              unsigned int* __restrict__ Abf_u,
                                              unsigned short* __restrict__ Wimg,
                                              int* __restrict__ cnt) {
    int bid = blockIdx.x, tid = threadIdx.x;
    if (bid < HIST_BLOCKS) {
        int base = bid * 1024 + tid;
#pragma unroll
        for (int k = 0; k < 4; k++)
            atomicAdd(&cnt[ei[N_EDGES + base + k * 256]], 1);
    } else if (bid < HIST_BLOCKS + PREPX_BLOCKS) {
        int t = (bid - HIST_BLOCKS) * 256 + tid;          // < N*32
        float4 v = reinterpret_cast<const float4*>(x)[t];
        unsigned int p0 = (unsigned int)f2bf(v.x) | ((unsigned int)f2bf(v.y) << 16);
        unsigned int p1 = (unsigned int)f2bf(v.z) | ((unsigned int)f2bf(v.w) << 16);
        int row = t >> 5, c = t & 31;
        reinterpret_cast<uint2*>(Abf_u)[(size_t)row * 64 + 32 + c] =
            make_uint2(p0, p1);
    } else {
        int t = (bid - HIST_BLOCKS - PREPX_BLOCKS) * 256 + tid;  // < 65536
        int k = t >> 8, n = t & 255;
        float v = (k < 128) ? Wl[k * 256 + n] : Wr[(k - 128) * 256 + n];
        Wimg[(size_t)(k >> 5) * 8192 + n * 32 + (k & 31)] = f2bf(v);
    }
}

// ---------------------------------------------------------------------------
// scan1_k: blockSums[b] = sum of cnt[256b .. 256b+255]  (wave-shfl reduce)
// ---------------------------------------------------------------------------
__global__ __launch_bounds__(256) void scan1_k(const int* __restrict__ cnt,
                                               int* __restrict__ blockSums) {
    __shared__ int lds[4];
    int tid = threadIdx.x, lane = tid & 63, wv = tid >> 6;
    int i = blockIdx.x * 256 + tid;
    int v = (i < N_NODES) ? cnt[i] : 0;
#pragma unroll
    for (int m = 1; m < 64; m <<= 1) v += __shfl_xor(v, m, 64);
    if (lane == 0) lds[wv] = v;
    __syncthreads();
    if (tid == 0) blockSums[blockIdx.x] = lds[0] + lds[1] + lds[2] + lds[3];
}

// ---------------------------------------------------------------------------
// scan23_k: row_start[i] = (sum of blockSums[<b]) + exclusive-scan-in-block
// ---------------------------------------------------------------------------
__global__ __launch_bounds__(256) void scan23_k(const int* __restrict__ cnt,
                                                const int* __restrict__ blockSums,
                                                int* __restrict__ row_start,
                                                int* __restrict__ cursor) {
    __shared__ int lds[8];   // [0..3] prefix-reduce partials, [4..7] wave sums
    int tid = threadIdx.x, lane = tid & 63, wv = tid >> 6;
    int b = (int)blockIdx.x;

    // prefix of blockSums (b <= 195 < 256: one strided element per thread)
    int acc = (tid < b) ? blockSums[tid] : 0;
#pragma unroll
    for (int m = 1; m < 64; m <<= 1) acc += __shfl_xor(acc, m, 64);

    // wave-level inclusive scan of cnt
    int i = b * 256 + tid;
    int v = (i < N_NODES) ? cnt[i] : 0;
    int inc = v;
#pragma unroll
    for (int off = 1; off < 64; off <<= 1) {
        int t = __shfl_up(inc, off, 64);
        if (lane >= off) inc += t;
    }
    if (lane == 0) lds[wv] = acc;
    if (lane == 63) lds[4 + wv] = inc;
    __syncthreads();
    int boff = lds[0] + lds[1] + lds[2] + lds[3];
    int woff = 0;
    for (int j = 0; j < wv; j++) woff += lds[4 + j];
    int rs = boff + woff + (inc - v);
    if (i < N_NODES) {
        row_start[i] = rs;
        cursor[i]    = rs;
    }
    if (i == N_NODES) row_start[N_NODES] = rs;
}

__global__ __launch_bounds__(256) void permute_k(const int* __restrict__ ei,
                                                 int* __restrict__ cursor,
                                                 int* __restrict__ sorted_src) {
    int e = blockIdx.x * 256 + threadIdx.x;
    if (e >= N_EDGES) return;
    int dst = ei[N_EDGES + e];
    int pos = atomicAdd(&cursor[dst], 1);
    sorted_src[pos] = ei[e];
}

// ---------------------------------------------------------------------------
// agg_k (R4 form): one wave per node. lane=(g=lane>>4, sub=lane&15); one b128
// load covers 4 edges, unroll x2 = 8 edges (2KB) in flight; shfl_xor(16,32)
// folds edge groups; writes bf16 mean into Abf cols 0..127.
// ---------------------------------------------------------------------------
__global__ __launch_bounds__(256) void agg_k(const int* __restrict__ row_start,
                                             const int* __restrict__ sorted_src,
                                             unsigned int* __restrict__ Abf_u) {
    int wid  = (blockIdx.x * 256 + threadIdx.x) >> 6;  // node, < N exactly
    int lane = threadIdx.x & 63;
    int g    = lane >> 4;
    int sub  = lane & 15;
    int beg = row_start[wid];
    int end = row_start[wid + 1];
    const uint4* X = reinterpret_cast<const uint4*>(Abf_u);  // row = 32 uint4

    float s[8];
#pragma unroll
    for (int j = 0; j < 8; j++) s[j] = 0.f;

    for (int i = beg; i < end; i += 8) {
        int e0 = i + g;
        int e1 = i + 4 + g;
        uint4 v0 = make_uint4(0, 0, 0, 0), v1 = make_uint4(0, 0, 0, 0);
        if (e0 < end) v0 = X[(size_t)sorted_src[e0] * 32 + 16 + sub];
        if (e1 < end) v1 = X[(size_t)sorted_src[e1] * 32 + 16 + sub];
        s[0] += bf2f(v0.x & 0xffffu) + bf2f(v1.x & 0xffffu);
        s[1] += bf2f(v0.x >> 16)     + bf2f(v1.x >> 16);
        s[2] += bf2f(v0.y & 0xffffu) + bf2f(v1.y & 0xffffu);
        s[3] += bf2f(v0.y >> 16)     + bf2f(v1.y >> 16);
        s[4] += bf2f(v0.z & 0xffffu) + bf2f(v1.z & 0xffffu);
        s[5] += bf2f(v0.z >> 16)     + bf2f(v1.z >> 16);
        s[6] += bf2f(v0.w & 0xffffu) + bf2f(v1.w & 0xffffu);
        s[7] += bf2f(v0.w >> 16)     + bf2f(v1.w >> 16);
    }

#pragma unroll
    for (int m = 16; m <= 32; m <<= 1)
#pragma unroll
        for (int j = 0; j < 8; j++) s[j] += __shfl_xor(s[j], m, 64);

    if (g == 0) {
        float inv = (end > beg) ? 1.0f / (float)(end - beg) : 0.0f;
        uint4 o;
        o.x = (unsigned int)f2bf(s[0] * inv) | ((unsigned int)f2bf(s[1] * inv) << 16);
        o.y = (unsigned int)f2bf(s[2] * inv) | ((unsigned int)f2bf(s[3] * inv) << 16);
        o.z = (unsigned int)f2bf(s[4] * inv) | ((unsigned int)f2bf(s[5] * inv) << 16);
        o.w = (unsigned int)f2bf(s[6] * inv) | ((unsigned int)f2bf(s[7] * inv) << 16);
        reinterpret_cast<uint4*>(Abf_u)[(size_t)wid * 32 + sub] = o;
    }
}

// ---------------------------------------------------------------------------
// gemm_k: out[N][256] = Abf[N][256] @ Wcat[256][256] + bl, bf16 MFMA.
// Stage full 64x256 A-tile (stride 264), ONE barrier, then unrolled
// barrier-free K-loop; B-frags loaded straight from global Wimg
// (coalesced: 16 rows x 64B = 1KB contiguous per wave-load).
// ---------------------------------------------------------------------------
__global__ __launch_bounds__(256) void gemm_k(const unsigned short* __restrict__ Abf,
                                              const unsigned short* __restrict__ Wimg,
                                              const float* __restrict__ bl,
                                              float* __restrict__ out) {
    __shared__ unsigned short As[64 * 264];

    int tid  = threadIdx.x;
    int w    = tid >> 6;
    int lane = tid & 63;
    int m15  = lane & 15;
    int quad = lane >> 4;
    int bm   = blockIdx.x * 64;

    // stage full A tile: 64 rows x 32 chunks of 8 bf16; 8 chunks/thread
#pragma unroll
    for (int s = 0; s < 8; s++) {
        int idx = s * 256 + tid;
        int r = idx >> 5, c = idx & 31;
        int grow = bm + r;
        short8 v = {0, 0, 0, 0, 0, 0, 0, 0};
        if (grow < N_NODES)
            v = *reinterpret_cast<const short8*>(Abf + (size_t)grow * 256 + c * 8);
        *reinterpret_cast<short8*>(As + r * 264 + c * 8) = v;
    }
    __syncthreads();  // the only barrier

    f32x4 zero4 = {0.f, 0.f, 0.f, 0.f};
    f32x4 acc[4][4];
#pragma unroll
    for (int rt = 0; rt < 4; rt++)
#pragma unroll
        for (int ct = 0; ct < 4; ct++) acc[rt][ct] = zero4;

#pragma unroll
    for (int kc = 0; kc < 8; kc++) {
        short8 Af[4], Bf[4];
#pragma unroll
        for (int rt = 0; rt < 4; rt++)
            Af[rt] = *reinterpret_cast<const short8*>(
                         As + (rt * 16 + m15) * 264 + kc * 32 + quad * 8);
#pragma unroll
        for (int ct = 0; ct < 4; ct++)
            Bf[ct] = *reinterpret_cast<const short8*>(
                         Wimg + (size_t)kc * 8192 +
                         (w * 64 + ct * 16 + m15) * 32 + quad * 8);
#pragma unroll
        for (int rt = 0; rt < 4; rt++)
#pragma unroll
            for (int ct = 0; ct < 4; ct++)
                acc[rt][ct] = __builtin_amdgcn_mfma_f32_16x16x32_bf16(
                    Af[rt], Bf[ct], acc[rt][ct], 0, 0, 0);
    }

    // epilogue: C/D layout col=lane&15, row=quad*4+reg
    float bias[4];
#pragma unroll
    for (int ct = 0; ct < 4; ct++) bias[ct] = bl[w * 64 + ct * 16 + m15];
#pragma unroll
    for (int rt = 0; rt < 4; rt++) {
        int rb = bm + rt * 16 + quad * 4;
#pragma unroll
        for (int r = 0; r < 4; r++) {
            int row = rb + r;
            if (row < N_NODES) {
#pragma unroll
                for (int ct = 0; ct < 4; ct++)
                    out[(size_t)row * 256 + w * 64 + ct * 16 + m15] =
                        acc[rt][ct][r] + bias[ct];
            }
        }
    }
}

extern "C" void kernel_launch(void* const* d_in, const int* in_sizes, int n_in,
                              void* d_out, int out_size, void* d_ws, size_t ws_size,
                              hipStream_t stream) {
    const float* x  = (const float*)d_in[0];
    const int*   ei = (const int*)d_in[1];   // [2, E] int32
    const float* Wl = (const float*)d_in[2];
    const float* bl = (const float*)d_in[3];
    const float* Wr = (const float*)d_in[4];
    float* out = (float*)d_out;

    // ws layout
    unsigned short* Abf  = (unsigned short*)d_ws;              // N*256 bf16
    unsigned short* Wimg = Abf + (size_t)N_NODES * 256;        // 65536 bf16
    int* cnt        = (int*)(Wimg + 65536);                    // N
    int* row_start  = cnt + N_NODES;                           // N+1
    int* cursor     = row_start + N_NODES + 1;                 // N
    int* blockSums  = cursor + N_NODES;                        // 256
    int* sorted_src = blockSums + 256;                         // E

    hipMemsetAsync(cnt, 0, N_NODES * sizeof(int), stream);

    prep_k<<<HIST_BLOCKS + PREPX_BLOCKS + WPREP_BLOCKS, 256, 0, stream>>>(
        x, ei, Wl, Wr, (unsigned int*)Abf, Wimg, cnt);
    scan1_k<<<SCAN_BLOCKS, 256, 0, stream>>>(cnt, blockSums);
    scan23_k<<<SCAN_BLOCKS, 256, 0, stream>>>(cnt, blockSums, row_start, cursor);
    permute_k<<<(N_EDGES + 255) / 256, 256, 0, stream>>>(ei, cursor, sorted_src);
    agg_k<<<(N_NODES * 64) / 256, 256, 0, stream>>>(row_start, sorted_src,
                                                    (unsigned int*)Abf);
    gemm_k<<<(N_NODES + 63) / 64, 256, 0, stream>>>(Abf, Wimg, bl, out);
}